// Round 2
// 1829.944 us; speedup vs baseline: 1.0783x; 1.0783x over previous
//
#include <hip/hip_runtime.h>
#include <stdint.h>

#define T_STEPS 256
#define BATCH 64
#define DIM 1024
#define HID 1024
#define RANK 256
#define FOURH 4096
#define M1 (T_STEPS * BATCH) // 16384

typedef __bf16 bf16_t;
typedef bf16_t bf16x8 __attribute__((ext_vector_type(8)));
typedef float f32x4 __attribute__((ext_vector_type(4)));

union frag_cast { uint4 u; bf16x8 v; };
union b_cast { unsigned long long ll[2]; bf16x8 v; };

__device__ __forceinline__ bf16x8 load_frag(const unsigned short* p) {
  frag_cast c; c.u = *reinterpret_cast<const uint4*>(p); return c.v;
}
__device__ __forceinline__ unsigned short f2bf(float f) {
  union { float f; uint32_t u; } v; v.f = f;
  uint32_t u = v.u;
  return (unsigned short)((u + 0x7fffu + ((u >> 16) & 1u)) >> 16);
}
__device__ __forceinline__ float bf2f(unsigned short h) {
  union { uint32_t u; float f; } v; v.u = ((uint32_t)h) << 16; return v.f;
}
// Branch-free fast gates: v_exp + v_rcp (~1e-7 rel err, negligible vs bf16 noise).
__device__ __forceinline__ float fsig(float x) {
  return __builtin_amdgcn_rcpf(1.f + __expf(-x));
}
__device__ __forceinline__ float ftanh(float x) {
  return 1.f - 2.f * __builtin_amdgcn_rcpf(1.f + __expf(2.f * x));
}

// Pack a [K x N] logical B matrix (f32 source) into MFMA B-fragment layout:
// frag (kc, nt): lane l slot s holds B[kc*32 + (l>>4)*8 + s][nt*16 + (l&15)].
__global__ void k_pack(const float* __restrict__ src, unsigned short* __restrict__ dst,
                       int NT, int ld, int transposed) {
  int id = blockIdx.x * blockDim.x + threadIdx.x;
  int lane = id & 63;
  int fi = id >> 6; // kc*NT + nt
  int nt = fi % NT, kc = fi / NT;
  int k0 = kc * 32 + ((lane >> 4) * 8);
  int n  = nt * 16 + (lane & 15);
  unsigned short vals[8];
  if (transposed) {
    const float* p = src + (size_t)n * ld + k0;
#pragma unroll
    for (int s = 0; s < 8; ++s) vals[s] = f2bf(p[s]);
  } else {
#pragma unroll
    for (int s = 0; s < 8; ++s) vals[s] = f2bf(src[(size_t)(k0 + s) * ld + n]);
  }
  union { unsigned short u16[8]; uint4 u; } o;
#pragma unroll
  for (int s = 0; s < 8; ++s) o.u16[s] = vals[s];
  *reinterpret_cast<uint4*>(dst + (size_t)id * 8) = o.u;
}

// corr_x[j] = dia_x[j%H] - dot(u_x[j%H,:], w_x[j,:]);  bias[j] = b_x[j]+b_h[j]
__global__ void k_coef(const float* __restrict__ u_x, const float* __restrict__ w_x,
                       const float* __restrict__ dia_x,
                       const float* __restrict__ b_x, const float* __restrict__ b_h,
                       float* __restrict__ corr, float* __restrict__ bias) {
  int wv = threadIdx.x >> 6, lane = threadIdx.x & 63;
  int j = blockIdx.x * 4 + wv;
  int e = j & (HID - 1);
  const float* up = u_x + (size_t)e * RANK + lane * 4;
  const float* wp = w_x + (size_t)j * RANK + lane * 4;
  float s = up[0] * wp[0] + up[1] * wp[1] + up[2] * wp[2] + up[3] * wp[3];
#pragma unroll
  for (int off = 32; off > 0; off >>= 1) s += __shfl_xor(s, off, 64);
  if (lane == 0) {
    corr[j] = dia_x[e] - s;
    bias[j] = b_x[j] + b_h[j];
  }
}

// Tagged h-exchange init: word = (tag16 << 16) | bf16(h).
// buf0 holds h(0) with tag 0; buf1 gets sentinel tag 0xFFFF (!= any real tag).
__global__ void k_init(const float* __restrict__ h0, uint32_t* __restrict__ hbuf) {
  int i = blockIdx.x * blockDim.x + threadIdx.x; // exactly BATCH*HID threads
  hbuf[i] = (uint32_t)f2bf(h0[i]);          // tag 0 | h0
  hbuf[BATCH * HID + i] = 0xFFFF0000u;      // sentinel
}

// C[M x 64*gridDim.x] = A_f32[M x 32*KC] @ packB, store bf16.
// dia != null: C is AhT [j][d]; override C[j][d] = dia[d] when d == j % HID.
__global__ void k_gemm_a32(const float* __restrict__ A, int lda,
                           const unsigned short* __restrict__ packB, int NTtot,
                           int KC, unsigned short* __restrict__ C, int ldc,
                           const float* __restrict__ dia) {
  int w = threadIdx.x >> 6, lane = threadIdx.x & 63;
  int q = lane >> 4, ln = lane & 15;
  int m0 = blockIdx.y * 64, n0 = blockIdx.x * 64;
  int arow = m0 + w * 16 + ln;
  f32x4 acc[4] = {};
  for (int kc = 0; kc < KC; ++kc) {
    const float* ap = A + (size_t)arow * lda + kc * 32 + q * 8;
    float4 x0 = *reinterpret_cast<const float4*>(ap);
    float4 x1 = *reinterpret_cast<const float4*>(ap + 4);
    bf16x8 a;
    a[0] = (bf16_t)x0.x; a[1] = (bf16_t)x0.y; a[2] = (bf16_t)x0.z; a[3] = (bf16_t)x0.w;
    a[4] = (bf16_t)x1.x; a[5] = (bf16_t)x1.y; a[6] = (bf16_t)x1.z; a[7] = (bf16_t)x1.w;
#pragma unroll
    for (int nt = 0; nt < 4; ++nt) {
      bf16x8 b = load_frag(packB + ((size_t)(kc * NTtot + blockIdx.x * 4 + nt) * 64 + lane) * 8);
      acc[nt] = __builtin_amdgcn_mfma_f32_16x16x32_bf16(a, b, acc[nt], 0, 0, 0);
    }
  }
#pragma unroll
  for (int nt = 0; nt < 4; ++nt) {
    int ccol = n0 + nt * 16 + ln;
#pragma unroll
    for (int r = 0; r < 4; ++r) {
      int crow = m0 + w * 16 + q * 4 + r;
      float v = acc[nt][r];
      if (dia != nullptr && ccol == (crow & (HID - 1))) v = dia[ccol];
      C[(size_t)crow * ldc + ccol] = f2bf(v);
    }
  }
}

// Repack AhT [j][d] (bf16) into per-(cg,gate,kc) B-fragment layout for k_rec.
__global__ void k_packAh(const unsigned short* __restrict__ AhT, unsigned short* __restrict__ dst) {
  int id = blockIdx.x * blockDim.x + threadIdx.x;
  int lane = id & 63;
  int fi = id >> 6;        // (cg*4+g)*32 + kc
  int kc = fi & 31;
  int g  = (fi >> 5) & 3;
  int cg = fi >> 7;
  int j  = g * HID + cg * 16 + (lane & 15);
  int d0 = kc * 32 + ((lane >> 4) * 8);
  uint4 v = *reinterpret_cast<const uint4*>(AhT + (size_t)j * HID + d0);
  *reinterpret_cast<uint4*>(dst + (size_t)id * 8) = v;
}

// gx[m][j] = P[m,:] @ w_xT[:,j] + x[m][j%H]*corr[j] + bias[j], store bf16.
__global__ void k_gemm2(const unsigned short* __restrict__ P,
                        const unsigned short* __restrict__ packWx,
                        const float* __restrict__ x,
                        const float* __restrict__ corr, const float* __restrict__ bias,
                        unsigned short* __restrict__ gx) {
  int w = threadIdx.x >> 6, lane = threadIdx.x & 63;
  int q = lane >> 4, ln = lane & 15;
  int m0 = blockIdx.y * 64, n0 = blockIdx.x * 64;
  int arow = m0 + w * 16 + ln;
  f32x4 acc[4] = {};
#pragma unroll
  for (int kc = 0; kc < 8; ++kc) {
    bf16x8 a = load_frag(P + (size_t)arow * RANK + kc * 32 + q * 8);
#pragma unroll
    for (int nt = 0; nt < 4; ++nt) {
      bf16x8 b = load_frag(packWx + ((size_t)(kc * 256 + blockIdx.x * 4 + nt) * 64 + lane) * 8);
      acc[nt] = __builtin_amdgcn_mfma_f32_16x16x32_bf16(a, b, acc[nt], 0, 0, 0);
    }
  }
#pragma unroll
  for (int nt = 0; nt < 4; ++nt) {
    int j = n0 + nt * 16 + ln;
    int e = j & (HID - 1);
    float cj = corr[j], bj = bias[j];
#pragma unroll
    for (int r = 0; r < 4; ++r) {
      int m = m0 + w * 16 + q * 4 + r;
      float v = acc[nt][r] + x[(size_t)m * DIM + e] * cj + bj;
      gx[(size_t)m * FOURH + j] = f2bf(v);
    }
  }
}

// Persistent recurrent kernel — TAG-IN-DATA exchange (no slots, no spin, no
// publish-drain):
//  - h stored as 4B words (tag16<<16 | bf16), written via 8B agent atomics.
//    The 4B word is the atomicity granule: tag and value always travel
//    together, so consumers poll the DATA ITSELF. Serial path per step is
//    ONE L3 round trip (the stage load) + compute, vs the old
//    stage-RT + publish-drain-RT + signal-detect-RT + 5 barriers.
//  - Double-buffer race freedom: a block can only overwrite h(t) with
//    h(t+2) after loading all tags of h(t+1), which requires every
//    group-mate to have published h(t+1) — i.e. to have finished reading
//    h(t). Skew within a bg-group is bounded at 1 step by the data dep.
//  - bg-groups (batch rows) decouple automatically: a block polls only its
//    own 16 rows, so a straggler in one batch group no longer stalls the
//    other three.
//  - amdgpu_waves_per_eu(1,1): 1 wave/EU so the volatile-pinned B
//    fragments (128 VGPRs) live in registers, not scratch.
__global__ __launch_bounds__(256, 1) __attribute__((amdgpu_waves_per_eu(1, 1)))
void k_rec(
    const unsigned short* __restrict__ pAh,
    const unsigned short* __restrict__ gx,
    const float* __restrict__ c0,
    uint32_t* __restrict__ hbuf,   // [2][BATCH][HID] tagged words
    float* __restrict__ out) {
  const int tid = threadIdx.x;
  const int w = tid >> 6, lane = tid & 63;
  const int q = lane >> 4, ln = lane & 15;
  const int blk = blockIdx.x;
  const int cg = blk & 63, bg = blk >> 6;

  // Pin B fragments in registers via volatile 8B scalar loads.
  unsigned long long bqa[32], bqb[32];
  const unsigned long long* pp = reinterpret_cast<const unsigned long long*>(pAh) +
                                 ((size_t)((cg * 4 + w) * 32) * 64 + lane) * 2;
#pragma unroll
  for (int kc = 0; kc < 32; ++kc) {
    bqa[kc] = *reinterpret_cast<const volatile unsigned long long*>(pp + (size_t)kc * 128);
    bqb[kc] = *reinterpret_cast<const volatile unsigned long long*>(pp + (size_t)kc * 128 + 1);
  }

  const int rb = tid >> 4, ee = tid & 15;
  const int brow = bg * 16 + rb;
  const int e = cg * 16 + ee;
  float c = c0[brow * HID + e];

  __shared__ unsigned short hstage[16][1032];  // +8 pad
  __shared__ float pre[4][16][17];             // +1 pad
  __shared__ unsigned short tile[16][16];

  size_t g0 = (size_t)brow * FOURH;
  float gx0 = bf2f(gx[g0 + e]);
  float gx1 = bf2f(gx[g0 + HID + e]);
  float gx2 = bf2f(gx[g0 + 2 * HID + e]);
  float gx3 = bf2f(gx[g0 + 3 * HID + e]);

  for (int t = 0; t < T_STEPS; ++t) {
    const int cur = t & 1;

    // ---- Stage h(t): tagged loads with per-chunk retry. ----
    // Thread covers words [tid*4, tid*4+4) of each of its 16 rows.
    const uint32_t* hb = hbuf + (size_t)cur * (BATCH * HID);
    const unsigned tagexp = (unsigned)t;
    unsigned long long va[16], vb[16];
    unsigned pend = 0xFFFFu;
    do {
#pragma unroll
      for (int i = 0; i < 16; ++i)
        if (pend & (1u << i)) {
          const unsigned long long* p = reinterpret_cast<const unsigned long long*>(
              hb + (size_t)(bg * 16 + i) * HID) + (size_t)tid * 2;
          va[i] = __hip_atomic_load(p, __ATOMIC_RELAXED, __HIP_MEMORY_SCOPE_AGENT);
          vb[i] = __hip_atomic_load(p + 1, __ATOMIC_RELAXED, __HIP_MEMORY_SCOPE_AGENT);
        }
#pragma unroll
      for (int i = 0; i < 16; ++i)
        if (pend & (1u << i)) {
          unsigned w0 = (unsigned)va[i], w1 = (unsigned)(va[i] >> 32);
          unsigned w2 = (unsigned)vb[i], w3 = (unsigned)(vb[i] >> 32);
          if (((w0 >> 16) == tagexp) && ((w1 >> 16) == tagexp) &&
              ((w2 >> 16) == tagexp) && ((w3 >> 16) == tagexp)) {
            unsigned lo = (w0 & 0xffffu) | (w1 << 16);
            unsigned hi = (w2 & 0xffffu) | (w3 << 16);
            *reinterpret_cast<unsigned long long*>(&hstage[i][tid * 4]) =
                ((unsigned long long)hi << 32) | lo;
            pend &= ~(1u << i);
          }
        }
    } while (pend);
    __syncthreads();  // hstage ready

    // Prefetch gx(t+1) now; completes under the MFMA chain + gates.
    const int tn = (t + 1 < T_STEPS) ? (t + 1) : t;
    const size_t gn = ((size_t)tn * BATCH + brow) * FOURH;
    unsigned short n0 = gx[gn + e];
    unsigned short n1 = gx[gn + HID + e];
    unsigned short n2 = gx[gn + 2 * HID + e];
    unsigned short n3 = gx[gn + 3 * HID + e];

    f32x4 a0 = {}, a1 = {}, a2 = {}, a3 = {};
#pragma unroll
    for (int kc = 0; kc < 32; kc += 4) {
      b_cast b0, b1, b2, b3;
      b0.ll[0] = bqa[kc];     b0.ll[1] = bqb[kc];
      b1.ll[0] = bqa[kc + 1]; b1.ll[1] = bqb[kc + 1];
      b2.ll[0] = bqa[kc + 2]; b2.ll[1] = bqb[kc + 2];
      b3.ll[0] = bqa[kc + 3]; b3.ll[1] = bqb[kc + 3];
      a0 = __builtin_amdgcn_mfma_f32_16x16x32_bf16(load_frag(&hstage[ln][(kc    ) * 32 + q * 8]), b0.v, a0, 0, 0, 0);
      a1 = __builtin_amdgcn_mfma_f32_16x16x32_bf16(load_frag(&hstage[ln][(kc + 1) * 32 + q * 8]), b1.v, a1, 0, 0, 0);
      a2 = __builtin_amdgcn_mfma_f32_16x16x32_bf16(load_frag(&hstage[ln][(kc + 2) * 32 + q * 8]), b2.v, a2, 0, 0, 0);
      a3 = __builtin_amdgcn_mfma_f32_16x16x32_bf16(load_frag(&hstage[ln][(kc + 3) * 32 + q * 8]), b3.v, a3, 0, 0, 0);
    }
#pragma unroll
    for (int r = 0; r < 4; ++r)
      pre[w][q * 4 + r][ln] = (a0[r] + a1[r]) + (a2[r] + a3[r]);
    __syncthreads();

    float p0 = pre[0][rb][ee] + gx0;
    float p1 = pre[1][rb][ee] + gx1;
    float p2 = pre[2][rb][ee] + gx2;
    float p3 = pre[3][rb][ee] + gx3;

    float gi = fsig(p0);
    float gf = fsig(p1);
    float go = fsig(p2);
    float gn_ = ftanh(p3);
    c = gf * c + gi * gn_;
    float hn = go * ftanh(c);
    tile[rb][ee] = f2bf(hn);
    __syncthreads();  // tile complete

    // Publish h(t+1) as tagged words (wave 0). No drain, no signal: the tag
    // rides in the same 4B word as the value.
    if (tid < 64) {
      int r2 = tid >> 2, cc = (tid & 3) * 4;
      unsigned long long tv = *reinterpret_cast<const unsigned long long*>(&tile[r2][cc]);
      unsigned tg = ((unsigned)(t + 1)) << 16;
      unsigned long long w01 =
          (unsigned long long)(tg | (unsigned)(tv & 0xffffu)) |
          ((unsigned long long)(tg | (unsigned)((tv >> 16) & 0xffffu)) << 32);
      unsigned long long w23 =
          (unsigned long long)(tg | (unsigned)((tv >> 32) & 0xffffu)) |
          ((unsigned long long)(tg | (unsigned)((tv >> 48) & 0xffffu)) << 32);
      unsigned long long* dst = reinterpret_cast<unsigned long long*>(
          hbuf + (size_t)(cur ^ 1) * (BATCH * HID) + (size_t)(bg * 16 + r2) * HID + cg * 16 + cc);
      __hip_atomic_store(dst, w01, __ATOMIC_RELAXED, __HIP_MEMORY_SCOPE_AGENT);
      __hip_atomic_store(dst + 1, w23, __ATOMIC_RELAXED, __HIP_MEMORY_SCOPE_AGENT);
    }

    // out stores: never read on device; ack overlaps the next stage-retry.
    out[((size_t)t * BATCH + brow) * HID + e] = hn;
    if (t == T_STEPS - 1) {
      out[(size_t)T_STEPS * BATCH * HID + brow * HID + e] = hn;              // h_f
      out[(size_t)T_STEPS * BATCH * HID + BATCH * HID + brow * HID + e] = c; // c_f
    }

    gx0 = bf2f(n0); gx1 = bf2f(n1); gx2 = bf2f(n2); gx3 = bf2f(n3);
  }
}

extern "C" void kernel_launch(void* const* d_in, const int* in_sizes, int n_in,
                              void* d_out, int out_size, void* d_ws, size_t ws_size,
                              hipStream_t stream) {
  const float* x     = (const float*)d_in[0];
  const float* h0    = (const float*)d_in[1];
  const float* c0    = (const float*)d_in[2];
  const float* u_x   = (const float*)d_in[3];
  const float* u_h   = (const float*)d_in[4];
  const float* w_x   = (const float*)d_in[5];
  const float* w_h   = (const float*)d_in[6];
  const float* b_x   = (const float*)d_in[7];
  const float* b_h   = (const float*)d_in[8];
  const float* dia_x = (const float*)d_in[9];
  const float* dia_h = (const float*)d_in[10];
  float* out = (float*)d_out;
  (void)in_sizes; (void)n_in; (void)out_size; (void)ws_size;

  char* base = (char*)d_ws;
  size_t off = 0;
  auto alloc = [&](size_t bytes) -> void* {
    void* p = base + off;
    off = (off + bytes + 255) & ~(size_t)255;
    return p;
  };
  unsigned short* pUx  = (unsigned short*)alloc((size_t)32 * 16 * 64 * 8 * 2);
  unsigned short* pUhT = (unsigned short*)alloc((size_t)8 * 64 * 64 * 8 * 2);
  unsigned short* pWx  = (unsigned short*)alloc((size_t)8 * 256 * 64 * 8 * 2);
  float* corr = (float*)alloc((size_t)FOURH * 4);
  float* bias = (float*)alloc((size_t)FOURH * 4);
  uint32_t* hbufT = (uint32_t*)alloc((size_t)2 * BATCH * HID * 4);  // tagged
  unsigned short* P    = (unsigned short*)alloc((size_t)M1 * RANK * 2);
  unsigned short* AhT  = (unsigned short*)alloc((size_t)FOURH * HID * 2);
  unsigned short* pAh  = (unsigned short*)alloc((size_t)64 * 4 * 32 * 64 * 8 * 2);
  unsigned short* gx   = (unsigned short*)alloc((size_t)M1 * FOURH * 2);

  // B-operand packs (one-time, reused by GEMMs / recurrence)
  k_pack<<<128, 256, 0, stream>>>(u_x, pUx, 16, RANK, 0);   // G1 B: u_x [1024 x 256]
  k_pack<<<128, 256, 0, stream>>>(u_h, pUhT, 64, RANK, 1);  // G3 B: u_hT [256 x 1024]
  k_pack<<<512, 256, 0, stream>>>(w_x, pWx, 256, RANK, 1);  // G2 B: w_xT [256 x 4096]
  k_coef<<<1024, 256, 0, stream>>>(u_x, w_x, dia_x, b_x, b_h, corr, bias);
  k_init<<<256, 256, 0, stream>>>(h0, hbufT);
  // G1: P[16384 x 256] = X @ u_x
  k_gemm_a32<<<dim3(4, 256), 256, 0, stream>>>(x, DIM, pUx, 16, 32, P, RANK, nullptr);
  // G3: AhT[4096 x 1024] = w_h @ u_hT, diagonal overridden with dia_h
  k_gemm_a32<<<dim3(16, 64), 256, 0, stream>>>(w_h, RANK, pUhT, 64, 8, AhT, HID, dia_h);
  k_packAh<<<2048, 256, 0, stream>>>(AhT, pAh);
  // G2: gx = P @ w_xT + x*corr + bias  (bf16)
  k_gemm2<<<dim3(64, 256), 256, 0, stream>>>(P, pWx, x, corr, bias, gx);
  // Persistent recurrence (tag-in-data exchange)
  k_rec<<<256, 256, 0, stream>>>(pAh, gx, c0, hbufT, out);
}

// Round 3
// 1571.062 us; speedup vs baseline: 1.2560x; 1.1648x over previous
//
#include <hip/hip_runtime.h>
#include <stdint.h>

#define T_STEPS 256
#define BATCH 64
#define DIM 1024
#define HID 1024
#define RANK 256
#define FOURH 4096
#define M1 (T_STEPS * BATCH) // 16384

typedef __bf16 bf16_t;
typedef bf16_t bf16x8 __attribute__((ext_vector_type(8)));
typedef float f32x4 __attribute__((ext_vector_type(4)));

union frag_cast { uint4 u; bf16x8 v; };
union b_cast { unsigned long long ll[2]; bf16x8 v; };

__device__ __forceinline__ bf16x8 load_frag(const unsigned short* p) {
  frag_cast c; c.u = *reinterpret_cast<const uint4*>(p); return c.v;
}
__device__ __forceinline__ unsigned short f2bf(float f) {
  union { float f; uint32_t u; } v; v.f = f;
  uint32_t u = v.u;
  return (unsigned short)((u + 0x7fffu + ((u >> 16) & 1u)) >> 16);
}
__device__ __forceinline__ float bf2f(unsigned short h) {
  union { uint32_t u; float f; } v; v.u = ((uint32_t)h) << 16; return v.f;
}
// Branch-free fast gates: v_exp + v_rcp (~1e-7 rel err, negligible vs bf16 noise).
__device__ __forceinline__ float fsig(float x) {
  return __builtin_amdgcn_rcpf(1.f + __expf(-x));
}
__device__ __forceinline__ float ftanh(float x) {
  return 1.f - 2.f * __builtin_amdgcn_rcpf(1.f + __expf(2.f * x));
}

// Pack a [K x N] logical B matrix (f32 source) into MFMA B-fragment layout:
// frag (kc, nt): lane l slot s holds B[kc*32 + (l>>4)*8 + s][nt*16 + (l&15)].
__global__ void k_pack(const float* __restrict__ src, unsigned short* __restrict__ dst,
                       int NT, int ld, int transposed) {
  int id = blockIdx.x * blockDim.x + threadIdx.x;
  int lane = id & 63;
  int fi = id >> 6; // kc*NT + nt
  int nt = fi % NT, kc = fi / NT;
  int k0 = kc * 32 + ((lane >> 4) * 8);
  int n  = nt * 16 + (lane & 15);
  unsigned short vals[8];
  if (transposed) {
    const float* p = src + (size_t)n * ld + k0;
#pragma unroll
    for (int s = 0; s < 8; ++s) vals[s] = f2bf(p[s]);
  } else {
#pragma unroll
    for (int s = 0; s < 8; ++s) vals[s] = f2bf(src[(size_t)(k0 + s) * ld + n]);
  }
  union { unsigned short u16[8]; uint4 u; } o;
#pragma unroll
  for (int s = 0; s < 8; ++s) o.u16[s] = vals[s];
  *reinterpret_cast<uint4*>(dst + (size_t)id * 8) = o.u;
}

// corr_x[j] = dia_x[j%H] - dot(u_x[j%H,:], w_x[j,:]);  bias[j] = b_x[j]+b_h[j]
__global__ void k_coef(const float* __restrict__ u_x, const float* __restrict__ w_x,
                       const float* __restrict__ dia_x,
                       const float* __restrict__ b_x, const float* __restrict__ b_h,
                       float* __restrict__ corr, float* __restrict__ bias) {
  int wv = threadIdx.x >> 6, lane = threadIdx.x & 63;
  int j = blockIdx.x * 4 + wv;
  int e = j & (HID - 1);
  const float* up = u_x + (size_t)e * RANK + lane * 4;
  const float* wp = w_x + (size_t)j * RANK + lane * 4;
  float s = up[0] * wp[0] + up[1] * wp[1] + up[2] * wp[2] + up[3] * wp[3];
#pragma unroll
  for (int off = 32; off > 0; off >>= 1) s += __shfl_xor(s, off, 64);
  if (lane == 0) {
    corr[j] = dia_x[e] - s;
    bias[j] = b_x[j] + b_h[j];
  }
}

// Tagged h-exchange init: word = (tag16 << 16) | bf16(h).
// buf0 holds h(0) with tag 0; buf1 gets sentinel tag 0xFFFF (!= any real tag).
__global__ void k_init(const float* __restrict__ h0, uint32_t* __restrict__ hbuf) {
  int i = blockIdx.x * blockDim.x + threadIdx.x; // exactly BATCH*HID threads
  hbuf[i] = (uint32_t)f2bf(h0[i]);          // tag 0 | h0
  hbuf[BATCH * HID + i] = 0xFFFF0000u;      // sentinel
}

// C[M x 64*gridDim.x] = A_f32[M x 32*KC] @ packB, store bf16.
// dia != null: C is AhT [j][d]; override C[j][d] = dia[d] when d == j % HID.
__global__ void k_gemm_a32(const float* __restrict__ A, int lda,
                           const unsigned short* __restrict__ packB, int NTtot,
                           int KC, unsigned short* __restrict__ C, int ldc,
                           const float* __restrict__ dia) {
  int w = threadIdx.x >> 6, lane = threadIdx.x & 63;
  int q = lane >> 4, ln = lane & 15;
  int m0 = blockIdx.y * 64, n0 = blockIdx.x * 64;
  int arow = m0 + w * 16 + ln;
  f32x4 acc[4] = {};
  for (int kc = 0; kc < KC; ++kc) {
    const float* ap = A + (size_t)arow * lda + kc * 32 + q * 8;
    float4 x0 = *reinterpret_cast<const float4*>(ap);
    float4 x1 = *reinterpret_cast<const float4*>(ap + 4);
    bf16x8 a;
    a[0] = (bf16_t)x0.x; a[1] = (bf16_t)x0.y; a[2] = (bf16_t)x0.z; a[3] = (bf16_t)x0.w;
    a[4] = (bf16_t)x1.x; a[5] = (bf16_t)x1.y; a[6] = (bf16_t)x1.z; a[7] = (bf16_t)x1.w;
#pragma unroll
    for (int nt = 0; nt < 4; ++nt) {
      bf16x8 b = load_frag(packB + ((size_t)(kc * NTtot + blockIdx.x * 4 + nt) * 64 + lane) * 8);
      acc[nt] = __builtin_amdgcn_mfma_f32_16x16x32_bf16(a, b, acc[nt], 0, 0, 0);
    }
  }
#pragma unroll
  for (int nt = 0; nt < 4; ++nt) {
    int ccol = n0 + nt * 16 + ln;
#pragma unroll
    for (int r = 0; r < 4; ++r) {
      int crow = m0 + w * 16 + q * 4 + r;
      float v = acc[nt][r];
      if (dia != nullptr && ccol == (crow & (HID - 1))) v = dia[ccol];
      C[(size_t)crow * ldc + ccol] = f2bf(v);
    }
  }
}

// Repack AhT [j][d] (bf16) into per-(cg,gate,kc) B-fragment layout for k_rec.
__global__ void k_packAh(const unsigned short* __restrict__ AhT, unsigned short* __restrict__ dst) {
  int id = blockIdx.x * blockDim.x + threadIdx.x;
  int lane = id & 63;
  int fi = id >> 6;        // (cg*4+g)*32 + kc
  int kc = fi & 31;
  int g  = (fi >> 5) & 3;
  int cg = fi >> 7;
  int j  = g * HID + cg * 16 + (lane & 15);
  int d0 = kc * 32 + ((lane >> 4) * 8);
  uint4 v = *reinterpret_cast<const uint4*>(AhT + (size_t)j * HID + d0);
  *reinterpret_cast<uint4*>(dst + (size_t)id * 8) = v;
}

// gx[m][j] = P[m,:] @ w_xT[:,j] + x[m][j%H]*corr[j] + bias[j], store bf16.
__global__ void k_gemm2(const unsigned short* __restrict__ P,
                        const unsigned short* __restrict__ packWx,
                        const float* __restrict__ x,
                        const float* __restrict__ corr, const float* __restrict__ bias,
                        unsigned short* __restrict__ gx) {
  int w = threadIdx.x >> 6, lane = threadIdx.x & 63;
  int q = lane >> 4, ln = lane & 15;
  int m0 = blockIdx.y * 64, n0 = blockIdx.x * 64;
  int arow = m0 + w * 16 + ln;
  f32x4 acc[4] = {};
#pragma unroll
  for (int kc = 0; kc < 8; ++kc) {
    bf16x8 a = load_frag(P + (size_t)arow * RANK + kc * 32 + q * 8);
#pragma unroll
    for (int nt = 0; nt < 4; ++nt) {
      bf16x8 b = load_frag(packWx + ((size_t)(kc * 256 + blockIdx.x * 4 + nt) * 64 + lane) * 8);
      acc[nt] = __builtin_amdgcn_mfma_f32_16x16x32_bf16(a, b, acc[nt], 0, 0, 0);
    }
  }
#pragma unroll
  for (int nt = 0; nt < 4; ++nt) {
    int j = n0 + nt * 16 + ln;
    int e = j & (HID - 1);
    float cj = corr[j], bj = bias[j];
#pragma unroll
    for (int r = 0; r < 4; ++r) {
      int m = m0 + w * 16 + q * 4 + r;
      float v = acc[nt][r] + x[(size_t)m * DIM + e] * cj + bj;
      gx[(size_t)m * FOURH + j] = f2bf(v);
    }
  }
}

// Persistent recurrent kernel — tag-in-data exchange, REQUEST-RATE optimized:
//  Theory (R2 post-mortem): uncached agent-scope loads are per-lane requests;
//  chip-wide UC-request ceiling ~148 req/cy explains both R0 (1.05M req ->
//  7k cy staging + 8k protocol) and R2 (2.1M req -> 14k cy staging).
//  This version cuts requests 4x:
//   - 128 blocks x 512 threads (8 waves = 2 gates-colhalves x 4 gates):
//     each block covers 16 rows x 32 cols x 4 gates, so the 16-row h tile
//     is staged by HALF as many blocks -> broadcast 16 -> 8 MB/step.
//   - Round-0 staging via 16B global_load_dwordx4 sc1 (agent scope,
//     same L3-coherent visibility as __hip_atomic_load; per-4B tags make
//     torn 16B reads harmless) -> 1 request per 16B instead of 2.
//     Chunks failing the tag check retry via the proven 8B atomic path,
//     so a coherence surprise degrades perf instead of hanging.
//  Publish stays on the known-good 8B relaxed agent atomic stores.
__global__ __launch_bounds__(512, 1) __attribute__((amdgpu_waves_per_eu(2, 2)))
void k_rec(
    const unsigned short* __restrict__ pAh,
    const unsigned short* __restrict__ gx,
    const float* __restrict__ c0,
    uint32_t* __restrict__ hbuf,   // [2][BATCH][HID] tagged words
    float* __restrict__ out) {
  const int tid = threadIdx.x;
  const int w = tid >> 6, lane = tid & 63;
  const int q = lane >> 4, ln = lane & 15;
  const int blk = blockIdx.x;
  const int cg2 = blk & 31, bg = blk >> 5;   // 32 col-blocks x 4 row-groups
  const int g = w & 3, ch2 = w >> 2;          // wave: gate g, col-half ch2
  const int cg_eff = cg2 * 2 + ch2;           // 16-col unit in [0,64)

  // Pin B fragments in registers via volatile 8B scalar loads.
  unsigned long long bqa[32], bqb[32];
  const unsigned long long* pp = reinterpret_cast<const unsigned long long*>(pAh) +
                                 ((size_t)((cg_eff * 4 + g) * 32) * 64 + lane) * 2;
#pragma unroll
  for (int kc = 0; kc < 32; ++kc) {
    bqa[kc] = *reinterpret_cast<const volatile unsigned long long*>(pp + (size_t)kc * 128);
    bqb[kc] = *reinterpret_cast<const volatile unsigned long long*>(pp + (size_t)kc * 128 + 1);
  }

  const int rb = tid >> 5, ee = tid & 31;     // post-proc: row rb, col ee (0..31)
  const int brow = bg * 16 + rb;
  const int e = cg2 * 32 + ee;
  float c = c0[brow * HID + e];

  __shared__ unsigned short hstage[16][1032];  // +8 pad
  __shared__ float pre[4][16][33];             // [gate][row][col], odd stride
  __shared__ unsigned short tile[16][32];

  size_t g0 = (size_t)brow * FOURH;
  float gx0 = bf2f(gx[g0 + e]);
  float gx1 = bf2f(gx[g0 + HID + e]);
  float gx2 = bf2f(gx[g0 + 2 * HID + e]);
  float gx3 = bf2f(gx[g0 + 3 * HID + e]);

  for (int t = 0; t < T_STEPS; ++t) {
    const int cur = t & 1;
    const uint32_t* hb = hbuf + (size_t)cur * (BATCH * HID);
    const unsigned tagexp = (unsigned)t;

    // ---- Stage h(t): round 0 = 16B sc1 loads; retries = 8B atomic loads. ----
    // Chunk c (0..7): ch = c*512+tid -> row = ch>>8, value-col vc = (ch&255)*4.
    uint4 r0, r1, r2, r3, r4, r5, r6, r7;
#define ISSUE16(cc, rr)                                                        \
    {                                                                          \
      int ch = cc * 512 + tid;                                                 \
      const uint32_t* p = hb + (((size_t)(bg * 16 + (ch >> 8))) << 10) +       \
                          ((ch & 255) << 2);                                   \
      asm volatile("global_load_dwordx4 %0, %1, off sc1"                       \
                   : "=&v"(rr) : "v"(p) : "memory");                           \
    }
    ISSUE16(0, r0) ISSUE16(1, r1) ISSUE16(2, r2) ISSUE16(3, r3)
    ISSUE16(4, r4) ISSUE16(5, r5) ISSUE16(6, r6) ISSUE16(7, r7)
#undef ISSUE16
    asm volatile("s_waitcnt vmcnt(0)" ::: "memory");
    __builtin_amdgcn_sched_barrier(0);

    unsigned pend = 0;
#define CHECK16(cc, rr)                                                        \
    {                                                                          \
      unsigned bad = ((rr.x >> 16) ^ tagexp) | ((rr.y >> 16) ^ tagexp) |       \
                     ((rr.z >> 16) ^ tagexp) | ((rr.w >> 16) ^ tagexp);        \
      if (bad == 0) {                                                          \
        int ch = cc * 512 + tid;                                               \
        unsigned lo = (rr.x & 0xffffu) | (rr.y << 16);                         \
        unsigned hi = (rr.z & 0xffffu) | (rr.w << 16);                         \
        *reinterpret_cast<unsigned long long*>(                                \
            &hstage[ch >> 8][(ch & 255) << 2]) =                               \
            ((unsigned long long)hi << 32) | lo;                               \
      } else pend |= 1u << cc;                                                 \
    }
    CHECK16(0, r0) CHECK16(1, r1) CHECK16(2, r2) CHECK16(3, r3)
    CHECK16(4, r4) CHECK16(5, r5) CHECK16(6, r6) CHECK16(7, r7)
#undef CHECK16

    int rounds = 0;
    while (pend) {
#pragma unroll
      for (int c2 = 0; c2 < 8; ++c2)
        if (pend & (1u << c2)) {
          int ch = c2 * 512 + tid;
          const unsigned long long* p = reinterpret_cast<const unsigned long long*>(
              hb + (((size_t)(bg * 16 + (ch >> 8))) << 10) + ((ch & 255) << 2));
          unsigned long long va = __hip_atomic_load(p, __ATOMIC_RELAXED,
                                                    __HIP_MEMORY_SCOPE_AGENT);
          unsigned long long vb = __hip_atomic_load(p + 1, __ATOMIC_RELAXED,
                                                    __HIP_MEMORY_SCOPE_AGENT);
          unsigned w0 = (unsigned)va, w1 = (unsigned)(va >> 32);
          unsigned w2 = (unsigned)vb, w3 = (unsigned)(vb >> 32);
          if (((w0 >> 16) == tagexp) && ((w1 >> 16) == tagexp) &&
              ((w2 >> 16) == tagexp) && ((w3 >> 16) == tagexp)) {
            unsigned lo = (w0 & 0xffffu) | (w1 << 16);
            unsigned hi = (w2 & 0xffffu) | (w3 << 16);
            *reinterpret_cast<unsigned long long*>(
                &hstage[ch >> 8][(ch & 255) << 2]) =
                ((unsigned long long)hi << 32) | lo;
            pend &= ~(1u << c2);
          }
        }
      if (pend && ++rounds > 2) __builtin_amdgcn_s_sleep(1);
    }
    __syncthreads();  // hstage ready

    // Prefetch gx(t+1) now; completes under the MFMA chain.
    const int tn = (t + 1 < T_STEPS) ? (t + 1) : t;
    const size_t gn = ((size_t)tn * BATCH + brow) * FOURH;
    unsigned short n0 = gx[gn + e];
    unsigned short n1 = gx[gn + HID + e];
    unsigned short n2 = gx[gn + 2 * HID + e];
    unsigned short n3 = gx[gn + 3 * HID + e];

    f32x4 a0 = {}, a1 = {}, a2 = {}, a3 = {};
#pragma unroll
    for (int kc = 0; kc < 32; kc += 4) {
      b_cast b0, b1, b2, b3;
      b0.ll[0] = bqa[kc];     b0.ll[1] = bqb[kc];
      b1.ll[0] = bqa[kc + 1]; b1.ll[1] = bqb[kc + 1];
      b2.ll[0] = bqa[kc + 2]; b2.ll[1] = bqb[kc + 2];
      b3.ll[0] = bqa[kc + 3]; b3.ll[1] = bqb[kc + 3];
      a0 = __builtin_amdgcn_mfma_f32_16x16x32_bf16(load_frag(&hstage[ln][(kc    ) * 32 + q * 8]), b0.v, a0, 0, 0, 0);
      a1 = __builtin_amdgcn_mfma_f32_16x16x32_bf16(load_frag(&hstage[ln][(kc + 1) * 32 + q * 8]), b1.v, a1, 0, 0, 0);
      a2 = __builtin_amdgcn_mfma_f32_16x16x32_bf16(load_frag(&hstage[ln][(kc + 2) * 32 + q * 8]), b2.v, a2, 0, 0, 0);
      a3 = __builtin_amdgcn_mfma_f32_16x16x32_bf16(load_frag(&hstage[ln][(kc + 3) * 32 + q * 8]), b3.v, a3, 0, 0, 0);
    }
#pragma unroll
    for (int r = 0; r < 4; ++r)
      pre[g][q * 4 + r][ch2 * 16 + ln] = (a0[r] + a1[r]) + (a2[r] + a3[r]);
    __syncthreads();

    float p0 = pre[0][rb][ee] + gx0;
    float p1 = pre[1][rb][ee] + gx1;
    float p2 = pre[2][rb][ee] + gx2;
    float p3 = pre[3][rb][ee] + gx3;

    float gi = fsig(p0);
    float gf = fsig(p1);
    float go = fsig(p2);
    float gn_ = ftanh(p3);
    c = gf * c + gi * gn_;
    float hn = go * ftanh(c);
    tile[rb][ee] = f2bf(hn);
    __syncthreads();  // tile complete

    // Publish h(t+1) as tagged words (first 2 waves; 8B relaxed agent atomics).
    if (tid < 128) {
      int r2_ = tid >> 3, c4 = (tid & 7) << 2;
      unsigned long long tv = *reinterpret_cast<const unsigned long long*>(&tile[r2_][c4]);
      unsigned tg = ((unsigned)(t + 1)) << 16;
      unsigned long long w01 =
          (unsigned long long)(tg | (unsigned)(tv & 0xffffu)) |
          ((unsigned long long)(tg | (unsigned)((tv >> 16) & 0xffffu)) << 32);
      unsigned long long w23 =
          (unsigned long long)(tg | (unsigned)((tv >> 32) & 0xffffu)) |
          ((unsigned long long)(tg | (unsigned)((tv >> 48) & 0xffffu)) << 32);
      unsigned long long* dst = reinterpret_cast<unsigned long long*>(
          hbuf + (size_t)(cur ^ 1) * (BATCH * HID) +
          (((size_t)(bg * 16 + r2_)) << 10) + cg2 * 32 + c4);
      __hip_atomic_store(dst, w01, __ATOMIC_RELAXED, __HIP_MEMORY_SCOPE_AGENT);
      __hip_atomic_store(dst + 1, w23, __ATOMIC_RELAXED, __HIP_MEMORY_SCOPE_AGENT);
    }

    // out stores: never read on device; ack overlaps the next stage round.
    out[((size_t)t * BATCH + brow) * HID + e] = hn;
    if (t == T_STEPS - 1) {
      out[(size_t)T_STEPS * BATCH * HID + brow * HID + e] = hn;              // h_f
      out[(size_t)T_STEPS * BATCH * HID + BATCH * HID + brow * HID + e] = c; // c_f
    }

    gx0 = bf2f(n0); gx1 = bf2f(n1); gx2 = bf2f(n2); gx3 = bf2f(n3);
  }
}

extern "C" void kernel_launch(void* const* d_in, const int* in_sizes, int n_in,
                              void* d_out, int out_size, void* d_ws, size_t ws_size,
                              hipStream_t stream) {
  const float* x     = (const float*)d_in[0];
  const float* h0    = (const float*)d_in[1];
  const float* c0    = (const float*)d_in[2];
  const float* u_x   = (const float*)d_in[3];
  const float* u_h   = (const float*)d_in[4];
  const float* w_x   = (const float*)d_in[5];
  const float* w_h   = (const float*)d_in[6];
  const float* b_x   = (const float*)d_in[7];
  const float* b_h   = (const float*)d_in[8];
  const float* dia_x = (const float*)d_in[9];
  const float* dia_h = (const float*)d_in[10];
  float* out = (float*)d_out;
  (void)in_sizes; (void)n_in; (void)out_size; (void)ws_size;

  char* base = (char*)d_ws;
  size_t off = 0;
  auto alloc = [&](size_t bytes) -> void* {
    void* p = base + off;
    off = (off + bytes + 255) & ~(size_t)255;
    return p;
  };
  unsigned short* pUx  = (unsigned short*)alloc((size_t)32 * 16 * 64 * 8 * 2);
  unsigned short* pUhT = (unsigned short*)alloc((size_t)8 * 64 * 64 * 8 * 2);
  unsigned short* pWx  = (unsigned short*)alloc((size_t)8 * 256 * 64 * 8 * 2);
  float* corr = (float*)alloc((size_t)FOURH * 4);
  float* bias = (float*)alloc((size_t)FOURH * 4);
  uint32_t* hbufT = (uint32_t*)alloc((size_t)2 * BATCH * HID * 4);  // tagged
  unsigned short* P    = (unsigned short*)alloc((size_t)M1 * RANK * 2);
  unsigned short* AhT  = (unsigned short*)alloc((size_t)FOURH * HID * 2);
  unsigned short* pAh  = (unsigned short*)alloc((size_t)64 * 4 * 32 * 64 * 8 * 2);
  unsigned short* gx   = (unsigned short*)alloc((size_t)M1 * FOURH * 2);

  // B-operand packs (one-time, reused by GEMMs / recurrence)
  k_pack<<<128, 256, 0, stream>>>(u_x, pUx, 16, RANK, 0);   // G1 B: u_x [1024 x 256]
  k_pack<<<128, 256, 0, stream>>>(u_h, pUhT, 64, RANK, 1);  // G3 B: u_hT [256 x 1024]
  k_pack<<<512, 256, 0, stream>>>(w_x, pWx, 256, RANK, 1);  // G2 B: w_xT [256 x 4096]
  k_coef<<<1024, 256, 0, stream>>>(u_x, w_x, dia_x, b_x, b_h, corr, bias);
  k_init<<<256, 256, 0, stream>>>(h0, hbufT);
  // G1: P[16384 x 256] = X @ u_x
  k_gemm_a32<<<dim3(4, 256), 256, 0, stream>>>(x, DIM, pUx, 16, 32, P, RANK, nullptr);
  // G3: AhT[4096 x 1024] = w_h @ u_hT, diagonal overridden with dia_h
  k_gemm_a32<<<dim3(16, 64), 256, 0, stream>>>(w_h, RANK, pUhT, 64, 8, AhT, HID, dia_h);
  k_packAh<<<2048, 256, 0, stream>>>(AhT, pAh);
  // G2: gx = P @ w_xT + x*corr + bias  (bf16)
  k_gemm2<<<dim3(64, 256), 256, 0, stream>>>(P, pWx, x, corr, bias, gx);
  // Persistent recurrence (tag-in-data, request-rate optimized)
  k_rec<<<128, 512, 0, stream>>>(pAh, gx, c0, hbufT, out);
}